// Round 1
// baseline (10764.306 us; speedup 1.0000x reference)
//
#include <hip/hip_runtime.h>

#define IN_F 256
#define OUT_F 256
#define BM 64
#define KB 32

// ---------------------------------------------------------------------------
// GEMM: sup[M][256] = x[M][256] @ w[256][256]  (fp32, vector ALU)
// Block: 256 threads, BM=64 rows/block. Thread tile: 8 rows x 8 cols
//   cg = t & 31  -> cols {cg*4..cg*4+3} and {128+cg*4..+3}
//   rg = t >> 5  -> rows rg*8 .. rg*8+7
// ---------------------------------------------------------------------------
__global__ __launch_bounds__(256) void gemm_kernel(
    const float* __restrict__ x, const float* __restrict__ w,
    float* __restrict__ sup, int M)
{
    __shared__ float xs[BM][KB + 4];     // +4 pad (keeps float4 alignment: 36*4=144B)
    __shared__ float ws[KB][OUT_F];

    const int t  = threadIdx.x;
    const int cg = t & 31;
    const int rg = t >> 5;
    const int brow = blockIdx.x * BM;

    float4 acc[8][2];
#pragma unroll
    for (int i = 0; i < 8; ++i) {
        acc[i][0] = make_float4(0.f, 0.f, 0.f, 0.f);
        acc[i][1] = make_float4(0.f, 0.f, 0.f, 0.f);
    }

    for (int k0 = 0; k0 < IN_F; k0 += KB) {
        // stage x tile: 64 rows x 32 k = 2048 floats -> 2 float4 per thread
        {
            const int rr = t >> 3;   // 0..31
            const int q  = t & 7;    // 0..7
#pragma unroll
            for (int h = 0; h < 2; ++h) {
                const int row = brow + rr + h * 32;
                float4 v = make_float4(0.f, 0.f, 0.f, 0.f);
                if (row < M)
                    v = *(const float4*)(x + (size_t)row * IN_F + k0 + q * 4);
                *(float4*)&xs[rr + h * 32][q * 4] = v;
            }
        }
        // stage w tile: 32 rows x 256 = 8192 floats -> 8 float4 per thread
        {
#pragma unroll
            for (int j = 0; j < 8; ++j) {
                const int flat = t + j * 256;        // one float4 each
                const int kr = flat >> 6;            // 0..31
                const int fc = (flat & 63) * 4;
                *(float4*)&ws[kr][fc] =
                    *(const float4*)(w + (size_t)(k0 + kr) * OUT_F + fc);
            }
        }
        __syncthreads();

#pragma unroll
        for (int kk = 0; kk < KB; kk += 4) {
            float4 xv[8];
#pragma unroll
            for (int i = 0; i < 8; ++i)
                xv[i] = *(const float4*)&xs[rg * 8 + i][kk];

            float4 wv[4][2];
#pragma unroll
            for (int kq = 0; kq < 4; ++kq) {
                wv[kq][0] = *(const float4*)&ws[kk + kq][cg * 4];
                wv[kq][1] = *(const float4*)&ws[kk + kq][128 + cg * 4];
            }
#pragma unroll
            for (int i = 0; i < 8; ++i) {
                const float* xk = reinterpret_cast<const float*>(&xv[i]);
#pragma unroll
                for (int kq = 0; kq < 4; ++kq) {
                    const float a = xk[kq];
                    acc[i][0].x = fmaf(a, wv[kq][0].x, acc[i][0].x);
                    acc[i][0].y = fmaf(a, wv[kq][0].y, acc[i][0].y);
                    acc[i][0].z = fmaf(a, wv[kq][0].z, acc[i][0].z);
                    acc[i][0].w = fmaf(a, wv[kq][0].w, acc[i][0].w);
                    acc[i][1].x = fmaf(a, wv[kq][1].x, acc[i][1].x);
                    acc[i][1].y = fmaf(a, wv[kq][1].y, acc[i][1].y);
                    acc[i][1].z = fmaf(a, wv[kq][1].z, acc[i][1].z);
                    acc[i][1].w = fmaf(a, wv[kq][1].w, acc[i][1].w);
                }
            }
        }
        __syncthreads();
    }

#pragma unroll
    for (int i = 0; i < 8; ++i) {
        const int row = brow + rg * 8 + i;
        if (row < M) {
            *(float4*)(sup + (size_t)row * OUT_F + cg * 4)       = acc[i][0];
            *(float4*)(sup + (size_t)row * OUT_F + 128 + cg * 4) = acc[i][1];
        }
    }
}

// ---------------------------------------------------------------------------
// out[i][f] = bias[f]   (float4 grid-stride)
// ---------------------------------------------------------------------------
__global__ __launch_bounds__(256) void bias_init_kernel(
    float* __restrict__ out, const float* __restrict__ bias, int total4)
{
    const float4* b4 = (const float4*)bias;
    float4* o4 = (float4*)out;
    for (int i = blockIdx.x * blockDim.x + threadIdx.x; i < total4;
         i += gridDim.x * blockDim.x) {
        o4[i] = b4[i & 63];
    }
}

// ---------------------------------------------------------------------------
// Edge scatter: one wave per edge. 64 lanes x float4 = 256 features.
//   out[row] += ew[e] * sup[col]
// ---------------------------------------------------------------------------
__global__ __launch_bounds__(256) void edge_scatter_kernel(
    const int* __restrict__ ei, const float* __restrict__ ew,
    const float* __restrict__ sup, float* __restrict__ out, int E)
{
    const int e = blockIdx.x * 4 + (threadIdx.x >> 6);
    if (e >= E) return;
    const int lane = threadIdx.x & 63;

    const int   row = ei[e];
    const int   col = ei[E + e];
    const float wgt = ew[e];

    const float4 s = *(const float4*)(sup + (size_t)col * OUT_F + lane * 4);
    float* o = out + (size_t)row * OUT_F + lane * 4;

    unsafeAtomicAdd(o + 0, wgt * s.x);
    unsafeAtomicAdd(o + 1, wgt * s.y);
    unsafeAtomicAdd(o + 2, wgt * s.z);
    unsafeAtomicAdd(o + 3, wgt * s.w);
}

// ---------------------------------------------------------------------------
extern "C" void kernel_launch(void* const* d_in, const int* in_sizes, int n_in,
                              void* d_out, int out_size, void* d_ws, size_t ws_size,
                              hipStream_t stream)
{
    const float* x    = (const float*)d_in[0];
    const int*   ei   = (const int*)d_in[1];
    const float* ew   = (const float*)d_in[2];
    const float* w    = (const float*)d_in[3];
    const float* bias = (const float*)d_in[4];
    float* out = (float*)d_out;
    float* sup = (float*)d_ws;          // [M][256] fp32 = 102.4 MB

    const int M = in_sizes[0] / IN_F;   // 100000
    const int E = in_sizes[2];          // 3,200,000

    // 1) support = x @ W
    gemm_kernel<<<(M + BM - 1) / BM, 256, 0, stream>>>(x, w, sup, M);

    // 2) out = bias (broadcast)
    const int total4 = M * OUT_F / 4;
    bias_init_kernel<<<2048, 256, 0, stream>>>(out, bias, total4);

    // 3) out[row] += ew * support[col]
    edge_scatter_kernel<<<(E + 3) / 4, 256, 0, stream>>>(ei, ew, sup, out, E);
}

// Round 2
// 994.363 us; speedup vs baseline: 10.8253x; 10.8253x over previous
//
#include <hip/hip_runtime.h>

#define IN_F 256
#define OUT_F 256
#define BM 64
#define KB 32

// ---------------------------------------------------------------------------
// GEMM: sup[M][256] = x[M][256] @ w[256][256]  (fp32, vector ALU) — unchanged
// ---------------------------------------------------------------------------
__global__ __launch_bounds__(256) void gemm_kernel(
    const float* __restrict__ x, const float* __restrict__ w,
    float* __restrict__ sup, int M)
{
    __shared__ float xs[BM][KB + 4];
    __shared__ float ws[KB][OUT_F];

    const int t  = threadIdx.x;
    const int cg = t & 31;
    const int rg = t >> 5;
    const int brow = blockIdx.x * BM;

    float4 acc[8][2];
#pragma unroll
    for (int i = 0; i < 8; ++i) {
        acc[i][0] = make_float4(0.f, 0.f, 0.f, 0.f);
        acc[i][1] = make_float4(0.f, 0.f, 0.f, 0.f);
    }

    for (int k0 = 0; k0 < IN_F; k0 += KB) {
        {
            const int rr = t >> 3;
            const int q  = t & 7;
#pragma unroll
            for (int h = 0; h < 2; ++h) {
                const int row = brow + rr + h * 32;
                float4 v = make_float4(0.f, 0.f, 0.f, 0.f);
                if (row < M)
                    v = *(const float4*)(x + (size_t)row * IN_F + k0 + q * 4);
                *(float4*)&xs[rr + h * 32][q * 4] = v;
            }
        }
        {
#pragma unroll
            for (int j = 0; j < 8; ++j) {
                const int flat = t + j * 256;
                const int kr = flat >> 6;
                const int fc = (flat & 63) * 4;
                *(float4*)&ws[kr][fc] =
                    *(const float4*)(w + (size_t)(k0 + kr) * OUT_F + fc);
            }
        }
        __syncthreads();

#pragma unroll
        for (int kk = 0; kk < KB; kk += 4) {
            float4 xv[8];
#pragma unroll
            for (int i = 0; i < 8; ++i)
                xv[i] = *(const float4*)&xs[rg * 8 + i][kk];

            float4 wv[4][2];
#pragma unroll
            for (int kq = 0; kq < 4; ++kq) {
                wv[kq][0] = *(const float4*)&ws[kk + kq][cg * 4];
                wv[kq][1] = *(const float4*)&ws[kk + kq][128 + cg * 4];
            }
#pragma unroll
            for (int i = 0; i < 8; ++i) {
                const float* xk = reinterpret_cast<const float*>(&xv[i]);
#pragma unroll
                for (int kq = 0; kq < 4; ++kq) {
                    const float a = xk[kq];
                    acc[i][0].x = fmaf(a, wv[kq][0].x, acc[i][0].x);
                    acc[i][0].y = fmaf(a, wv[kq][0].y, acc[i][0].y);
                    acc[i][0].z = fmaf(a, wv[kq][0].z, acc[i][0].z);
                    acc[i][0].w = fmaf(a, wv[kq][0].w, acc[i][0].w);
                    acc[i][1].x = fmaf(a, wv[kq][1].x, acc[i][1].x);
                    acc[i][1].y = fmaf(a, wv[kq][1].y, acc[i][1].y);
                    acc[i][1].z = fmaf(a, wv[kq][1].z, acc[i][1].z);
                    acc[i][1].w = fmaf(a, wv[kq][1].w, acc[i][1].w);
                }
            }
        }
        __syncthreads();
    }

#pragma unroll
    for (int i = 0; i < 8; ++i) {
        const int row = brow + rg * 8 + i;
        if (row < M) {
            *(float4*)(sup + (size_t)row * OUT_F + cg * 4)       = acc[i][0];
            *(float4*)(sup + (size_t)row * OUT_F + 128 + cg * 4) = acc[i][1];
        }
    }
}

// ---------------------------------------------------------------------------
// CSR build, step 1: per-row edge counts
// ---------------------------------------------------------------------------
__global__ __launch_bounds__(256) void count_kernel(
    const int* __restrict__ ei, int* __restrict__ counts, int E)
{
    const int e = blockIdx.x * blockDim.x + threadIdx.x;
    if (e < E) atomicAdd(&counts[ei[e]], 1);
}

// ---------------------------------------------------------------------------
// CSR build, step 2: segment assignment (no scan needed — placement order
// is arbitrary; segments are disjoint+contiguous which is all we need).
// cursor[row] = segment start (will be advanced to segment END by scatter).
// ---------------------------------------------------------------------------
__global__ __launch_bounds__(256) void segment_kernel(
    const int* __restrict__ counts, int* __restrict__ cursor,
    int* __restrict__ gcnt, int n)
{
    const int i = blockIdx.x * blockDim.x + threadIdx.x;
    if (i < n) cursor[i] = atomicAdd(gcnt, counts[i]);
}

// ---------------------------------------------------------------------------
// CSR build, step 3: bucket edges (col, weight) by destination row
// ---------------------------------------------------------------------------
__global__ __launch_bounds__(256) void bucket_kernel(
    const int* __restrict__ ei, const float* __restrict__ ew,
    int* __restrict__ cursor, int* __restrict__ scol,
    float* __restrict__ swgt, int E)
{
    const int e = blockIdx.x * blockDim.x + threadIdx.x;
    if (e < E) {
        const int row = ei[e];
        const int pos = atomicAdd(&cursor[row], 1);
        scol[pos] = ei[E + e];
        swgt[pos] = ew[e];
    }
}

// ---------------------------------------------------------------------------
// Pull: one wave per destination row. 64 lanes x float4 = 256 features
// accumulated in registers; single store. Zero fp32 atomics.
// ---------------------------------------------------------------------------
__global__ __launch_bounds__(256) void pull_kernel(
    const int* __restrict__ counts, const int* __restrict__ cursor,
    const int* __restrict__ scol, const float* __restrict__ swgt,
    const float* __restrict__ sup, const float* __restrict__ bias,
    float* __restrict__ out, int n)
{
    const int row = blockIdx.x * 4 + (threadIdx.x >> 6);
    if (row >= n) return;
    const int lane = threadIdx.x & 63;

    const int cnt   = counts[row];
    const int start = cursor[row] - cnt;   // cursor == segment end after bucket

    float4 acc = *(const float4*)(bias + lane * 4);

    for (int j0 = 0; j0 < cnt; j0 += 64) {
        // coalesced load of up to 64 (col,w) pairs, then shfl-broadcast
        int   mycol = 0;
        float myw   = 0.f;
        if (j0 + lane < cnt) {
            mycol = scol[start + j0 + lane];
            myw   = swgt[start + j0 + lane];
        }
        const int m = min(64, cnt - j0);

        int j = 0;
        for (; j + 4 <= m; j += 4) {        // 4-way ILP on the gathers
            const int   c0 = __shfl(mycol, j),     c1 = __shfl(mycol, j + 1);
            const int   c2 = __shfl(mycol, j + 2), c3 = __shfl(mycol, j + 3);
            const float w0 = __shfl(myw, j),       w1 = __shfl(myw, j + 1);
            const float w2 = __shfl(myw, j + 2),   w3 = __shfl(myw, j + 3);
            const float4 s0 = *(const float4*)(sup + (size_t)c0 * OUT_F + lane * 4);
            const float4 s1 = *(const float4*)(sup + (size_t)c1 * OUT_F + lane * 4);
            const float4 s2 = *(const float4*)(sup + (size_t)c2 * OUT_F + lane * 4);
            const float4 s3 = *(const float4*)(sup + (size_t)c3 * OUT_F + lane * 4);
            acc.x = fmaf(w0, s0.x, acc.x); acc.y = fmaf(w0, s0.y, acc.y);
            acc.z = fmaf(w0, s0.z, acc.z); acc.w = fmaf(w0, s0.w, acc.w);
            acc.x = fmaf(w1, s1.x, acc.x); acc.y = fmaf(w1, s1.y, acc.y);
            acc.z = fmaf(w1, s1.z, acc.z); acc.w = fmaf(w1, s1.w, acc.w);
            acc.x = fmaf(w2, s2.x, acc.x); acc.y = fmaf(w2, s2.y, acc.y);
            acc.z = fmaf(w2, s2.z, acc.z); acc.w = fmaf(w2, s2.w, acc.w);
            acc.x = fmaf(w3, s3.x, acc.x); acc.y = fmaf(w3, s3.y, acc.y);
            acc.z = fmaf(w3, s3.z, acc.z); acc.w = fmaf(w3, s3.w, acc.w);
        }
        for (; j < m; ++j) {
            const int   c = __shfl(mycol, j);
            const float wj = __shfl(myw, j);
            const float4 s = *(const float4*)(sup + (size_t)c * OUT_F + lane * 4);
            acc.x = fmaf(wj, s.x, acc.x); acc.y = fmaf(wj, s.y, acc.y);
            acc.z = fmaf(wj, s.z, acc.z); acc.w = fmaf(wj, s.w, acc.w);
        }
    }

    *(float4*)(out + (size_t)row * OUT_F + lane * 4) = acc;
}

// --------------------------- fallback (R0) path ---------------------------
__global__ __launch_bounds__(256) void bias_init_kernel(
    float* __restrict__ out, const float* __restrict__ bias, int total4)
{
    const float4* b4 = (const float4*)bias;
    float4* o4 = (float4*)out;
    for (int i = blockIdx.x * blockDim.x + threadIdx.x; i < total4;
         i += gridDim.x * blockDim.x)
        o4[i] = b4[i & 63];
}

__global__ __launch_bounds__(256) void edge_scatter_kernel(
    const int* __restrict__ ei, const float* __restrict__ ew,
    const float* __restrict__ sup, float* __restrict__ out, int E)
{
    const int e = blockIdx.x * 4 + (threadIdx.x >> 6);
    if (e >= E) return;
    const int lane = threadIdx.x & 63;
    const int   row = ei[e];
    const int   col = ei[E + e];
    const float wgt = ew[e];
    const float4 s = *(const float4*)(sup + (size_t)col * OUT_F + lane * 4);
    float* o = out + (size_t)row * OUT_F + lane * 4;
    unsafeAtomicAdd(o + 0, wgt * s.x);
    unsafeAtomicAdd(o + 1, wgt * s.y);
    unsafeAtomicAdd(o + 2, wgt * s.z);
    unsafeAtomicAdd(o + 3, wgt * s.w);
}

// ---------------------------------------------------------------------------
extern "C" void kernel_launch(void* const* d_in, const int* in_sizes, int n_in,
                              void* d_out, int out_size, void* d_ws, size_t ws_size,
                              hipStream_t stream)
{
    const float* x    = (const float*)d_in[0];
    const int*   ei   = (const int*)d_in[1];
    const float* ew   = (const float*)d_in[2];
    const float* w    = (const float*)d_in[3];
    const float* bias = (const float*)d_in[4];
    float* out = (float*)d_out;

    const int M = in_sizes[0] / IN_F;   // 100000
    const int E = in_sizes[2];          // 3,200,000

    // workspace layout (256B-aligned)
    char* p = (char*)d_ws;
    const size_t sup_b    = (size_t)M * OUT_F * sizeof(float);   // 102.4 MB
    const size_t counts_b = ((size_t)M * 4 + 255) & ~255ull;
    const size_t cursor_b = counts_b;
    const size_t gcnt_b   = 256;
    const size_t scol_b   = ((size_t)E * 4 + 255) & ~255ull;
    const size_t swgt_b   = scol_b;
    const size_t need     = sup_b + counts_b + cursor_b + gcnt_b + scol_b + swgt_b;

    float* sup    = (float*)p;                 p += sup_b;
    int*   counts = (int*)p;                   p += counts_b;
    int*   cursor = (int*)p;                   p += cursor_b;
    int*   gcnt   = (int*)p;                   p += gcnt_b;
    int*   scol   = (int*)p;                   p += scol_b;
    float* swgt   = (float*)p;

    // 1) support = x @ W
    gemm_kernel<<<(M + BM - 1) / BM, 256, 0, stream>>>(x, w, sup, M);

    if (ws_size >= need) {
        // 2) CSR build (unordered segments)
        hipMemsetAsync(counts, 0, (size_t)M * 4, stream);
        hipMemsetAsync(gcnt, 0, 4, stream);
        count_kernel<<<(E + 255) / 256, 256, 0, stream>>>(ei, counts, E);
        segment_kernel<<<(M + 255) / 256, 256, 0, stream>>>(counts, cursor, gcnt, M);
        bucket_kernel<<<(E + 255) / 256, 256, 0, stream>>>(ei, ew, cursor, scol, swgt, E);
        // 3) pull + bias, one wave per row, no fp32 atomics
        pull_kernel<<<(M + 3) / 4, 256, 0, stream>>>(
            counts, cursor, scol, swgt, sup, bias, out, M);
    } else {
        // fallback: R0 atomic path (needs only sup)
        const int total4 = M * OUT_F / 4;
        bias_init_kernel<<<2048, 256, 0, stream>>>(out, bias, total4);
        edge_scatter_kernel<<<(E + 3) / 4, 256, 0, stream>>>(ei, ew, sup, out, E);
    }
}

// Round 3
// 770.932 us; speedup vs baseline: 13.9627x; 1.2898x over previous
//
#include <hip/hip_runtime.h>
#include <hip/hip_fp16.h>

#define IN_F 256
#define OUT_F 256
#define BM 64
#define KB 32

__device__ inline unsigned pack_half2(float a, float b) {
    __half2 h = __floats2half2_rn(a, b);
    return *reinterpret_cast<unsigned*>(&h);
}

// ---------------------------------------------------------------------------
// GEMM: sup16[M][256] = fp16( x[M][256] @ w[256][256] )  (fp32 VALU compute)
// ---------------------------------------------------------------------------
__global__ __launch_bounds__(256) void gemm_kernel(
    const float* __restrict__ x, const float* __restrict__ w,
    __half* __restrict__ sup16, int M)
{
    __shared__ float xs[BM][KB + 4];
    __shared__ float ws[KB][OUT_F];

    const int t  = threadIdx.x;
    const int cg = t & 31;
    const int rg = t >> 5;
    const int brow = blockIdx.x * BM;

    float4 acc[8][2];
#pragma unroll
    for (int i = 0; i < 8; ++i) {
        acc[i][0] = make_float4(0.f, 0.f, 0.f, 0.f);
        acc[i][1] = make_float4(0.f, 0.f, 0.f, 0.f);
    }

    for (int k0 = 0; k0 < IN_F; k0 += KB) {
        {
            const int rr = t >> 3;
            const int q  = t & 7;
#pragma unroll
            for (int h = 0; h < 2; ++h) {
                const int row = brow + rr + h * 32;
                float4 v = make_float4(0.f, 0.f, 0.f, 0.f);
                if (row < M)
                    v = *(const float4*)(x + (size_t)row * IN_F + k0 + q * 4);
                *(float4*)&xs[rr + h * 32][q * 4] = v;
            }
        }
        {
#pragma unroll
            for (int j = 0; j < 8; ++j) {
                const int flat = t + j * 256;
                const int kr = flat >> 6;
                const int fc = (flat & 63) * 4;
                *(float4*)&ws[kr][fc] =
                    *(const float4*)(w + (size_t)(k0 + kr) * OUT_F + fc);
            }
        }
        __syncthreads();

#pragma unroll
        for (int kk = 0; kk < KB; kk += 4) {
            float4 xv[8];
#pragma unroll
            for (int i = 0; i < 8; ++i)
                xv[i] = *(const float4*)&xs[rg * 8 + i][kk];

            float4 wv[4][2];
#pragma unroll
            for (int kq = 0; kq < 4; ++kq) {
                wv[kq][0] = *(const float4*)&ws[kk + kq][cg * 4];
                wv[kq][1] = *(const float4*)&ws[kk + kq][128 + cg * 4];
            }
#pragma unroll
            for (int i = 0; i < 8; ++i) {
                const float* xk = reinterpret_cast<const float*>(&xv[i]);
#pragma unroll
                for (int kq = 0; kq < 4; ++kq) {
                    const float a = xk[kq];
                    acc[i][0].x = fmaf(a, wv[kq][0].x, acc[i][0].x);
                    acc[i][0].y = fmaf(a, wv[kq][0].y, acc[i][0].y);
                    acc[i][0].z = fmaf(a, wv[kq][0].z, acc[i][0].z);
                    acc[i][0].w = fmaf(a, wv[kq][0].w, acc[i][0].w);
                    acc[i][1].x = fmaf(a, wv[kq][1].x, acc[i][1].x);
                    acc[i][1].y = fmaf(a, wv[kq][1].y, acc[i][1].y);
                    acc[i][1].z = fmaf(a, wv[kq][1].z, acc[i][1].z);
                    acc[i][1].w = fmaf(a, wv[kq][1].w, acc[i][1].w);
                }
            }
        }
        __syncthreads();
    }

#pragma unroll
    for (int i = 0; i < 8; ++i) {
        const int row = brow + rg * 8 + i;
        if (row < M) {
            uint2 lo, hi;
            lo.x = pack_half2(acc[i][0].x, acc[i][0].y);
            lo.y = pack_half2(acc[i][0].z, acc[i][0].w);
            hi.x = pack_half2(acc[i][1].x, acc[i][1].y);
            hi.y = pack_half2(acc[i][1].z, acc[i][1].w);
            *(uint2*)(sup16 + (size_t)row * OUT_F + cg * 4)       = lo;
            *(uint2*)(sup16 + (size_t)row * OUT_F + 128 + cg * 4) = hi;
        }
    }
}

// ---------------------------------------------------------------------------
// CSR build
// ---------------------------------------------------------------------------
__global__ __launch_bounds__(256) void count_kernel(
    const int* __restrict__ ei, int* __restrict__ counts, int E)
{
    const int e = blockIdx.x * blockDim.x + threadIdx.x;
    if (e < E) atomicAdd(&counts[ei[e]], 1);
}

__global__ __launch_bounds__(256) void segment_kernel(
    const int* __restrict__ counts, int* __restrict__ cursor,
    int* __restrict__ gcnt, int n)
{
    const int i = blockIdx.x * blockDim.x + threadIdx.x;
    if (i < n) cursor[i] = atomicAdd(gcnt, counts[i]);
}

__global__ __launch_bounds__(256) void bucket_kernel(
    const int* __restrict__ ei, const float* __restrict__ ew,
    int* __restrict__ cursor, int* __restrict__ scol,
    float* __restrict__ swgt, int E)
{
    const int e = blockIdx.x * blockDim.x + threadIdx.x;
    if (e < E) {
        const int row = ei[e];
        const int pos = atomicAdd(&cursor[row], 1);
        scol[pos] = ei[E + e];
        swgt[pos] = ew[e];
    }
}

// ---------------------------------------------------------------------------
// Pull: one wave per row; lane holds 4 features (8 B fp16 per gather).
// ---------------------------------------------------------------------------
__global__ __launch_bounds__(256) void pull_kernel(
    const int* __restrict__ counts, const int* __restrict__ cursor,
    const int* __restrict__ scol, const float* __restrict__ swgt,
    const __half* __restrict__ sup16, const float* __restrict__ bias,
    float* __restrict__ out, int n)
{
    const int row = blockIdx.x * 4 + (threadIdx.x >> 6);
    if (row >= n) return;
    const int lane = threadIdx.x & 63;

    const int cnt   = counts[row];
    const int start = cursor[row] - cnt;

    float4 acc = *(const float4*)(bias + lane * 4);

#define GATHER_FMA(c, wt)                                                     \
    {                                                                         \
        const uint2 v = *(const uint2*)(sup16 + (size_t)(c) * OUT_F + lane * 4); \
        const float2 f0 = __half22float2(*(const __half2*)&v.x);              \
        const float2 f1 = __half22float2(*(const __half2*)&v.y);              \
        acc.x = fmaf((wt), f0.x, acc.x); acc.y = fmaf((wt), f0.y, acc.y);     \
        acc.z = fmaf((wt), f1.x, acc.z); acc.w = fmaf((wt), f1.y, acc.w);     \
    }

    for (int j0 = 0; j0 < cnt; j0 += 64) {
        int   mycol = 0;
        float myw   = 0.f;
        if (j0 + lane < cnt) {
            mycol = scol[start + j0 + lane];
            myw   = swgt[start + j0 + lane];
        }
        const int m = min(64, cnt - j0);

        int j = 0;
        for (; j + 4 <= m; j += 4) {
            const int   c0 = __shfl(mycol, j),     c1 = __shfl(mycol, j + 1);
            const int   c2 = __shfl(mycol, j + 2), c3 = __shfl(mycol, j + 3);
            const float w0 = __shfl(myw, j),       w1 = __shfl(myw, j + 1);
            const float w2 = __shfl(myw, j + 2),   w3 = __shfl(myw, j + 3);
            GATHER_FMA(c0, w0);
            GATHER_FMA(c1, w1);
            GATHER_FMA(c2, w2);
            GATHER_FMA(c3, w3);
        }
        for (; j < m; ++j) {
            const int   c = __shfl(mycol, j);
            const float wj = __shfl(myw, j);
            GATHER_FMA(c, wj);
        }
    }
#undef GATHER_FMA

    *(float4*)(out + (size_t)row * OUT_F + lane * 4) = acc;
}

// --------------------------- fallback path ---------------------------
__global__ __launch_bounds__(256) void bias_init_kernel(
    float* __restrict__ out, const float* __restrict__ bias, int total4)
{
    const float4* b4 = (const float4*)bias;
    float4* o4 = (float4*)out;
    for (int i = blockIdx.x * blockDim.x + threadIdx.x; i < total4;
         i += gridDim.x * blockDim.x)
        o4[i] = b4[i & 63];
}

__global__ __launch_bounds__(256) void edge_scatter_kernel(
    const int* __restrict__ ei, const float* __restrict__ ew,
    const __half* __restrict__ sup16, float* __restrict__ out, int E)
{
    const int e = blockIdx.x * 4 + (threadIdx.x >> 6);
    if (e >= E) return;
    const int lane = threadIdx.x & 63;
    const int   row = ei[e];
    const int   col = ei[E + e];
    const float wgt = ew[e];
    const uint2 v = *(const uint2*)(sup16 + (size_t)col * OUT_F + lane * 4);
    const float2 f0 = __half22float2(*(const __half2*)&v.x);
    const float2 f1 = __half22float2(*(const __half2*)&v.y);
    float* o = out + (size_t)row * OUT_F + lane * 4;
    unsafeAtomicAdd(o + 0, wgt * f0.x);
    unsafeAtomicAdd(o + 1, wgt * f0.y);
    unsafeAtomicAdd(o + 2, wgt * f1.x);
    unsafeAtomicAdd(o + 3, wgt * f1.y);
}

// ---------------------------------------------------------------------------
extern "C" void kernel_launch(void* const* d_in, const int* in_sizes, int n_in,
                              void* d_out, int out_size, void* d_ws, size_t ws_size,
                              hipStream_t stream)
{
    const float* x    = (const float*)d_in[0];
    const int*   ei   = (const int*)d_in[1];
    const float* ew   = (const float*)d_in[2];
    const float* w    = (const float*)d_in[3];
    const float* bias = (const float*)d_in[4];
    float* out = (float*)d_out;

    const int M = in_sizes[0] / IN_F;   // 100000
    const int E = in_sizes[2];          // 3,200,000

    char* p = (char*)d_ws;
    const size_t sup_b    = (((size_t)M * OUT_F * sizeof(__half)) + 255) & ~255ull; // 51.2 MB
    const size_t counts_b = ((size_t)M * 4 + 255) & ~255ull;
    const size_t cursor_b = counts_b;
    const size_t gcnt_b   = 256;
    const size_t scol_b   = ((size_t)E * 4 + 255) & ~255ull;
    const size_t swgt_b   = scol_b;
    const size_t need     = sup_b + counts_b + cursor_b + gcnt_b + scol_b + swgt_b;

    __half* sup16 = (__half*)p;                p += sup_b;
    int*    counts = (int*)p;                  p += counts_b;
    int*    cursor = (int*)p;                  p += cursor_b;
    int*    gcnt   = (int*)p;                  p += gcnt_b;
    int*    scol   = (int*)p;                  p += scol_b;
    float*  swgt   = (float*)p;

    // 1) support = fp16(x @ W)
    gemm_kernel<<<(M + BM - 1) / BM, 256, 0, stream>>>(x, w, sup16, M);

    if (ws_size >= need) {
        hipMemsetAsync(counts, 0, (size_t)M * 4, stream);
        hipMemsetAsync(gcnt, 0, 4, stream);
        count_kernel<<<(E + 255) / 256, 256, 0, stream>>>(ei, counts, E);
        segment_kernel<<<(M + 255) / 256, 256, 0, stream>>>(counts, cursor, gcnt, M);
        bucket_kernel<<<(E + 255) / 256, 256, 0, stream>>>(ei, ew, cursor, scol, swgt, E);
        pull_kernel<<<(M + 3) / 4, 256, 0, stream>>>(
            counts, cursor, scol, swgt, sup16, bias, out, M);
    } else {
        const int total4 = M * OUT_F / 4;
        bias_init_kernel<<<2048, 256, 0, stream>>>(out, bias, total4);
        edge_scatter_kernel<<<(E + 3) / 4, 256, 0, stream>>>(ei, ew, sup16, out, E);
    }
}

// Round 4
// 731.235 us; speedup vs baseline: 14.7207x; 1.0543x over previous
//
#include <hip/hip_runtime.h>
#include <hip/hip_fp16.h>

#define IN_F 256
#define OUT_F 256

using bf16x8 = __attribute__((ext_vector_type(8))) short;
using f32x4  = __attribute__((ext_vector_type(4))) float;

__device__ inline short bf16rne(float f) {
    unsigned u = __float_as_uint(f);
    u = u + 0x7FFFu + ((u >> 16) & 1u);     // round-to-nearest-even
    return (short)(u >> 16);
}
__device__ inline unsigned pack_half2(float a, float b) {
    __half2 h = __floats2half2_rn(a, b);
    return *reinterpret_cast<unsigned*>(&h);
}

// ---------------------------------------------------------------------------
// wt[n][k] = bf16(w[k][n])  — 128 KB, done once, L2-resident afterwards
// ---------------------------------------------------------------------------
__global__ __launch_bounds__(256) void convert_wt_kernel(
    const float* __restrict__ w, short* __restrict__ wt)
{
    const int idx = blockIdx.x * blockDim.x + threadIdx.x;   // 65536
    const int c = idx >> 8, k = idx & 255;
    wt[(size_t)c * IN_F + k] = bf16rne(w[(size_t)k * OUT_F + c]);
}

// ---------------------------------------------------------------------------
// MFMA GEMM: sup16[M][256] = fp16( x @ W ), zero LDS.
// Per block: 64 rows x 256 cols. 4 waves; wave w owns cols w*64..w*64+63.
// D = mfma(wt_frag, x_frag):  D[c][r] = sum_k w[k][c] x[r][k]
//   A(wt): m = lane&15 (col c), k = 8*(lane>>4)+j   (16B contiguous load)
//   B(x):  n = lane&15 (row r), k = 8*(lane>>4)+j   (fp32->bf16 in-reg)
//   D:     row(c) = 4*(lane>>4)+reg, col(r) = lane&15
//   => lane holds 4 consecutive cols of one sup row -> packed 8B fp16 store.
// ---------------------------------------------------------------------------
__global__ __launch_bounds__(256) void mfma_gemm_kernel(
    const float* __restrict__ x, const short* __restrict__ wt,
    __half* __restrict__ sup16, int M)
{
    const int lane = threadIdx.x & 63;
    const int wid  = threadIdx.x >> 6;
    const int l15  = lane & 15;
    const int l4   = lane >> 4;
    const int rowbase = blockIdx.x * 64;
    const int cbase   = wid * 64;

    f32x4 acc[4][4];
#pragma unroll
    for (int rt = 0; rt < 4; ++rt)
#pragma unroll
        for (int ct = 0; ct < 4; ++ct)
            acc[rt][ct] = (f32x4){0.f, 0.f, 0.f, 0.f};

    const float* xp[4];
    const short* wp[4];
#pragma unroll
    for (int rt = 0; rt < 4; ++rt) {
        int r = rowbase + rt * 16 + l15;
        if (r > M - 1) r = M - 1;                 // clamp; OOB rows not stored
        xp[rt] = x + (size_t)r * IN_F + l4 * 8;
    }
#pragma unroll
    for (int ct = 0; ct < 4; ++ct)
        wp[ct] = wt + (size_t)(cbase + ct * 16 + l15) * IN_F + l4 * 8;

#pragma unroll
    for (int k0 = 0; k0 < IN_F; k0 += 32) {
        bf16x8 b[4];
#pragma unroll
        for (int ct = 0; ct < 4; ++ct)
            b[ct] = *(const bf16x8*)(wp[ct] + k0);

        bf16x8 a[4];
#pragma unroll
        for (int rt = 0; rt < 4; ++rt) {
            const f32x4 f0 = __builtin_nontemporal_load((const f32x4*)(xp[rt] + k0));
            const f32x4 f1 = __builtin_nontemporal_load((const f32x4*)(xp[rt] + k0) + 1);
            bf16x8 v;
            v[0] = bf16rne(f0[0]); v[1] = bf16rne(f0[1]);
            v[2] = bf16rne(f0[2]); v[3] = bf16rne(f0[3]);
            v[4] = bf16rne(f1[0]); v[5] = bf16rne(f1[1]);
            v[6] = bf16rne(f1[2]); v[7] = bf16rne(f1[3]);
            a[rt] = v;
        }

#pragma unroll
        for (int rt = 0; rt < 4; ++rt)
#pragma unroll
            for (int ct = 0; ct < 4; ++ct)
                acc[rt][ct] = __builtin_amdgcn_mfma_f32_16x16x32_bf16(
                    b[ct], a[rt], acc[rt][ct], 0, 0, 0);
    }

#pragma unroll
    for (int rt = 0; rt < 4; ++rt) {
        const int r = rowbase + rt * 16 + l15;
        if (r >= M) continue;
#pragma unroll
        for (int ct = 0; ct < 4; ++ct) {
            uint2 pk;
            pk.x = pack_half2(acc[rt][ct][0], acc[rt][ct][1]);
            pk.y = pack_half2(acc[rt][ct][2], acc[rt][ct][3]);
            *(uint2*)(sup16 + (size_t)r * OUT_F + cbase + ct * 16 + l4 * 4) = pk;
        }
    }
}

// ---------------------------------------------------------------------------
// CSR build
// ---------------------------------------------------------------------------
__global__ __launch_bounds__(256) void count_kernel(
    const int* __restrict__ ei, int* __restrict__ counts, int E)
{
    const int e = blockIdx.x * blockDim.x + threadIdx.x;
    if (e < E) atomicAdd(&counts[__builtin_nontemporal_load(ei + e)], 1);
}

__global__ __launch_bounds__(256) void segment_kernel(
    const int* __restrict__ counts, int* __restrict__ cursor,
    int* __restrict__ gcnt, int n)
{
    const int i = blockIdx.x * blockDim.x + threadIdx.x;
    if (i < n) cursor[i] = atomicAdd(gcnt, counts[i]);
}

__global__ __launch_bounds__(256) void bucket_kernel(
    const int* __restrict__ ei, const float* __restrict__ ew,
    int* __restrict__ cursor, unsigned long long* __restrict__ scw, int E)
{
    const int e = blockIdx.x * blockDim.x + threadIdx.x;
    if (e < E) {
        const int      row = __builtin_nontemporal_load(ei + e);
        const int      col = __builtin_nontemporal_load(ei + E + e);
        const unsigned wb  = __builtin_nontemporal_load((const unsigned*)ew + e);
        const int pos = atomicAdd(&cursor[row], 1);
        scw[pos] = ((unsigned long long)wb << 32) | (unsigned)col;   // 1x 8B store
    }
}

// ---------------------------------------------------------------------------
// Pull: one wave per row; NT stream of (col,w); cached fp16 gather; NT out.
// ---------------------------------------------------------------------------
__global__ __launch_bounds__(256) void pull_kernel(
    const int* __restrict__ counts, const int* __restrict__ cursor,
    const unsigned long long* __restrict__ scw,
    const __half* __restrict__ sup16, const float* __restrict__ bias,
    float* __restrict__ out, int n)
{
    const int row = blockIdx.x * 4 + (threadIdx.x >> 6);
    if (row >= n) return;
    const int lane = threadIdx.x & 63;

    const int cnt   = counts[row];
    const int start = cursor[row] - cnt;

    float4 acc = *(const float4*)(bias + lane * 4);

#define GATHER_FMA(c, wt)                                                     \
    {                                                                         \
        const uint2 v = *(const uint2*)(sup16 + (size_t)(c) * OUT_F + lane * 4); \
        const float2 f0 = __half22float2(*(const __half2*)&v.x);              \
        const float2 f1 = __half22float2(*(const __half2*)&v.y);              \
        acc.x = fmaf((wt), f0.x, acc.x); acc.y = fmaf((wt), f0.y, acc.y);     \
        acc.z = fmaf((wt), f1.x, acc.z); acc.w = fmaf((wt), f1.y, acc.w);     \
    }

    for (int j0 = 0; j0 < cnt; j0 += 64) {
        unsigned long long pr = 0ull;
        if (j0 + lane < cnt)
            pr = __builtin_nontemporal_load(scw + start + j0 + lane);
        int   mycol = (int)(unsigned)pr;
        float myw   = __uint_as_float((unsigned)(pr >> 32));
        const int m = min(64, cnt - j0);

        int j = 0;
        for (; j + 4 <= m; j += 4) {
            const int   c0 = __shfl(mycol, j),     c1 = __shfl(mycol, j + 1);
            const int   c2 = __shfl(mycol, j + 2), c3 = __shfl(mycol, j + 3);
            const float w0 = __shfl(myw, j),       w1 = __shfl(myw, j + 1);
            const float w2 = __shfl(myw, j + 2),   w3 = __shfl(myw, j + 3);
            GATHER_FMA(c0, w0);
            GATHER_FMA(c1, w1);
            GATHER_FMA(c2, w2);
            GATHER_FMA(c3, w3);
        }
        for (; j < m; ++j) {
            const int   c  = __shfl(mycol, j);
            const float wj = __shfl(myw, j);
            GATHER_FMA(c, wj);
        }
    }
#undef GATHER_FMA

    f32x4 o; o[0] = acc.x; o[1] = acc.y; o[2] = acc.z; o[3] = acc.w;
    __builtin_nontemporal_store(o, (f32x4*)(out + (size_t)row * OUT_F + lane * 4));
}

// --------------------------- fallback path ---------------------------
__global__ __launch_bounds__(256) void bias_init_kernel(
    float* __restrict__ out, const float* __restrict__ bias, int total4)
{
    const float4* b4 = (const float4*)bias;
    float4* o4 = (float4*)out;
    for (int i = blockIdx.x * blockDim.x + threadIdx.x; i < total4;
         i += gridDim.x * blockDim.x)
        o4[i] = b4[i & 63];
}

__global__ __launch_bounds__(256) void edge_scatter_kernel(
    const int* __restrict__ ei, const float* __restrict__ ew,
    const __half* __restrict__ sup16, float* __restrict__ out, int E)
{
    const int e = blockIdx.x * 4 + (threadIdx.x >> 6);
    if (e >= E) return;
    const int lane = threadIdx.x & 63;
    const int   row = ei[e];
    const int   col = ei[E + e];
    const float wgt = ew[e];
    const uint2 v = *(const uint2*)(sup16 + (size_t)col * OUT_F + lane * 4);
    const float2 f0 = __half22float2(*(const __half2*)&v.x);
    const float2 f1 = __half22float2(*(const __half2*)&v.y);
    float* o = out + (size_t)row * OUT_F + lane * 4;
    unsafeAtomicAdd(o + 0, wgt * f0.x);
    unsafeAtomicAdd(o + 1, wgt * f0.y);
    unsafeAtomicAdd(o + 2, wgt * f1.x);
    unsafeAtomicAdd(o + 3, wgt * f1.y);
}

// ---------------------------------------------------------------------------
extern "C" void kernel_launch(void* const* d_in, const int* in_sizes, int n_in,
                              void* d_out, int out_size, void* d_ws, size_t ws_size,
                              hipStream_t stream)
{
    const float* x    = (const float*)d_in[0];
    const int*   ei   = (const int*)d_in[1];
    const float* ew   = (const float*)d_in[2];
    const float* w    = (const float*)d_in[3];
    const float* bias = (const float*)d_in[4];
    float* out = (float*)d_out;

    const int M = in_sizes[0] / IN_F;   // 100000
    const int E = in_sizes[2];          // 3,200,000

    // workspace layout: sup16 | counts | gcnt | cursor | scw | wt
    char* p = (char*)d_ws;
    const size_t sup_b    = (((size_t)M * OUT_F * sizeof(__half)) + 255) & ~255ull;
    const size_t counts_b = ((size_t)M * 4 + 255) & ~255ull;
    const size_t gcnt_b   = 256;
    const size_t cursor_b = counts_b;
    const size_t scw_b    = ((size_t)E * 8 + 255) & ~255ull;
    const size_t wt_b     = (size_t)IN_F * OUT_F * sizeof(short);
    const size_t need     = sup_b + counts_b + gcnt_b + cursor_b + scw_b + wt_b;

    __half* sup16  = (__half*)p;               p += sup_b;
    int*    counts = (int*)p;                  p += counts_b;
    int*    gcnt   = (int*)p;                  p += gcnt_b;
    int*    cursor = (int*)p;                  p += cursor_b;
    unsigned long long* scw = (unsigned long long*)p;  p += scw_b;
    short*  wtb    = (short*)p;

    // 1) wt = bf16(w^T); sup16 = fp16(x @ W) via MFMA
    convert_wt_kernel<<<(IN_F * OUT_F) / 256, 256, 0, stream>>>(w, wtb);
    mfma_gemm_kernel<<<(M + 63) / 64, 256, 0, stream>>>(x, wtb, sup16, M);

    if (ws_size >= need) {
        hipMemsetAsync(counts, 0, counts_b + gcnt_b, stream);  // counts + gcnt
        count_kernel<<<(E + 255) / 256, 256, 0, stream>>>(ei, counts, E);
        segment_kernel<<<(M + 255) / 256, 256, 0, stream>>>(counts, cursor, gcnt, M);
        bucket_kernel<<<(E + 255) / 256, 256, 0, stream>>>(ei, ew, cursor, scw, E);
        pull_kernel<<<(M + 3) / 4, 256, 0, stream>>>(
            counts, cursor, scw, sup16, bias, out, M);
    } else {
        const int total4 = M * OUT_F / 4;
        bias_init_kernel<<<2048, 256, 0, stream>>>(out, bias, total4);
        edge_scatter_kernel<<<(E + 3) / 4, 256, 0, stream>>>(ei, ew, sup16, out, E);
    }
}